// Round 1
// baseline (304.799 us; speedup 1.0000x reference)
//
#include <hip/hip_runtime.h>
#include <math.h>

#define NN   50000
#define EE   800000
#define INF_ 256
#define HID  128
#define OUTF 64
#define CAP  96
#define SLOPE 0.2f

__device__ __forceinline__ float lrelu(float x) { return x > 0.f ? x : SLOPE * x; }
__device__ __forceinline__ float4 lrelu4(float4 v) {
  v.x = lrelu(v.x); v.y = lrelu(v.y); v.z = lrelu(v.z); v.w = lrelu(v.w); return v;
}

// ---------------- GEMM1: feat1 = x @ W1  (50000x256 @ 256x128) ----------------
__global__ __launch_bounds__(256) void gemm1_k(const float* __restrict__ x,
                                               const float* __restrict__ W,
                                               float* __restrict__ feat) {
  const int TN = 64, TK = 32;
  __shared__ float xs[TK][TN + 1];
  __shared__ float wsh[TK][HID];
  int t = threadIdx.x;
  int n0 = blockIdx.x * TN;
  int tc = t & 31;          // cols tc*4 .. tc*4+3
  int tr = t >> 5;          // rows tr*8 .. tr*8+7
  float4 acc[8];
#pragma unroll
  for (int i = 0; i < 8; ++i) acc[i] = make_float4(0.f, 0.f, 0.f, 0.f);

  for (int k0 = 0; k0 < INF_; k0 += TK) {
#pragma unroll
    for (int i = 0; i < 2; ++i) {
      int idx = t + i * 256;          // 0..511
      int r   = idx >> 3;             // 0..63
      int c4  = idx & 7;              // 0..7
      int row = n0 + r;
      float4 v = make_float4(0.f, 0.f, 0.f, 0.f);
      if (row < NN) v = *(const float4*)&x[row * INF_ + k0 + c4 * 4];
      xs[c4 * 4 + 0][r] = v.x; xs[c4 * 4 + 1][r] = v.y;
      xs[c4 * 4 + 2][r] = v.z; xs[c4 * 4 + 3][r] = v.w;
    }
#pragma unroll
    for (int i = 0; i < 4; ++i) {
      int idx = t + i * 256;          // 0..1023
      int kk  = idx >> 5;             // 0..31
      int c4  = idx & 31;             // 0..31
      *(float4*)&wsh[kk][c4 * 4] = *(const float4*)&W[(k0 + kk) * HID + c4 * 4];
    }
    __syncthreads();
#pragma unroll
    for (int kk = 0; kk < TK; ++kk) {
      float4 w = *(const float4*)&wsh[kk][tc * 4];
#pragma unroll
      for (int i = 0; i < 8; ++i) {
        float xv = xs[kk][tr * 8 + i];
        acc[i].x += xv * w.x; acc[i].y += xv * w.y;
        acc[i].z += xv * w.z; acc[i].w += xv * w.w;
      }
    }
    __syncthreads();
  }
#pragma unroll
  for (int i = 0; i < 8; ++i) {
    int row = n0 + tr * 8 + i;
    if (row < NN) *(float4*)&feat[row * HID + tc * 4] = acc[i];
  }
}

// ---------------- attention scores layer 1: el/er [N,4] ----------------
__global__ __launch_bounds__(256) void scores1_k(const float* __restrict__ feat1,
                                                 const float* __restrict__ al,
                                                 const float* __restrict__ ar,
                                                 float* __restrict__ el,
                                                 float* __restrict__ er) {
  int wid = threadIdx.x >> 6, lane = threadIdx.x & 63;
  int n = blockIdx.x * 4 + wid;
  float f0 = feat1[n * HID + lane];
  float f1 = feat1[n * HID + 64 + lane];
  float pe0 = f0 * al[lane],      pe1 = f1 * al[64 + lane];
  float pr0 = f0 * ar[lane],      pr1 = f1 * ar[64 + lane];
#pragma unroll
  for (int off = 1; off < 32; off <<= 1) {
    pe0 += __shfl_xor(pe0, off); pe1 += __shfl_xor(pe1, off);
    pr0 += __shfl_xor(pr0, off); pr1 += __shfl_xor(pr1, off);
  }
  if ((lane & 31) == 0) {
    int hh = lane >> 5;               // 0 or 1
    el[n * 4 + hh]     = pe0;  el[n * 4 + 2 + hh] = pe1;
    er[n * 4 + hh]     = pr0;  er[n * 4 + 2 + hh] = pr1;
  }
}

// ---------------- scatter edges into per-dst buckets ----------------
__global__ __launch_bounds__(256) void scatter_k(const int* __restrict__ src,
                                                 const int* __restrict__ dst,
                                                 int* __restrict__ counts,
                                                 int* __restrict__ bucket) {
  int i = blockIdx.x * blockDim.x + threadIdx.x;
  if (i >= EE) return;
  int d = dst[i];
  int s = src[i];
  int pos = atomicAdd(&counts[d], 1);
  if (pos < CAP) bucket[d * CAP + pos] = s;
}

// ---------------- layer-1 softmax + aggregation, one wave per node ----------------
__global__ __launch_bounds__(256) void agg1_k(const float* __restrict__ feat1,
                                              const float* __restrict__ el1,
                                              const float* __restrict__ er1,
                                              const float* __restrict__ b1,
                                              const int* __restrict__ counts,
                                              const int* __restrict__ bucket,
                                              float* __restrict__ hout) {
  __shared__ float ee[4][CAP * 4];
  int wid = threadIdx.x >> 6, lane = threadIdx.x & 63;
  int n = blockIdx.x * 4 + wid;
  int deg = counts[n]; if (deg > CAP) deg = CAP;
  float4 er = *(const float4*)(er1 + n * 4);

  float4 mx = make_float4(-INFINITY, -INFINITY, -INFINITY, -INFINITY);
  for (int j = lane; j < deg; j += 64) {
    int s = bucket[n * CAP + j];
    float4 e4 = *(const float4*)(el1 + s * 4);
    float4 sc = lrelu4(make_float4(e4.x + er.x, e4.y + er.y, e4.z + er.z, e4.w + er.w));
    mx.x = fmaxf(mx.x, sc.x); mx.y = fmaxf(mx.y, sc.y);
    mx.z = fmaxf(mx.z, sc.z); mx.w = fmaxf(mx.w, sc.w);
  }
#pragma unroll
  for (int off = 1; off < 64; off <<= 1) {
    mx.x = fmaxf(mx.x, __shfl_xor(mx.x, off));
    mx.y = fmaxf(mx.y, __shfl_xor(mx.y, off));
    mx.z = fmaxf(mx.z, __shfl_xor(mx.z, off));
    mx.w = fmaxf(mx.w, __shfl_xor(mx.w, off));
  }
  float4 zs = make_float4(0.f, 0.f, 0.f, 0.f);
  for (int j = lane; j < deg; j += 64) {
    int s = bucket[n * CAP + j];
    float4 e4 = *(const float4*)(el1 + s * 4);
    float4 sc = lrelu4(make_float4(e4.x + er.x, e4.y + er.y, e4.z + er.z, e4.w + er.w));
    float4 ex = make_float4(__expf(sc.x - mx.x), __expf(sc.y - mx.y),
                            __expf(sc.z - mx.z), __expf(sc.w - mx.w));
    *(float4*)&ee[wid][j * 4] = ex;
    zs.x += ex.x; zs.y += ex.y; zs.z += ex.z; zs.w += ex.w;
  }
#pragma unroll
  for (int off = 1; off < 64; off <<= 1) {
    zs.x += __shfl_xor(zs.x, off); zs.y += __shfl_xor(zs.y, off);
    zs.z += __shfl_xor(zs.z, off); zs.w += __shfl_xor(zs.w, off);
  }
  __syncthreads();
  float iz1 = 0.f, iz2 = 0.f;
  if (deg > 0) {
    iz1 = 1.0f / ((lane < 32) ? zs.x : zs.y);
    iz2 = 1.0f / ((lane < 32) ? zs.z : zs.w);
  }
  int hsel = (lane >> 5) & 1;
  float acc0 = 0.f, acc1 = 0.f;
  const int base = n * CAP;
  for (int j = 0; j < deg; ++j) {
    int s = bucket[base + j];
    float a0 = ee[wid][j * 4 + hsel] * iz1;
    float a1 = ee[wid][j * 4 + 2 + hsel] * iz2;
    acc0 += feat1[s * HID + lane] * a0;
    acc1 += feat1[s * HID + 64 + lane] * a1;
  }
  float o0 = acc0 + b1[lane];
  float o1 = acc1 + b1[64 + lane];
  hout[n * HID + lane]      = fmaxf(o0, 0.f);
  hout[n * HID + 64 + lane] = fmaxf(o1, 0.f);
}

// ---------------- GEMM2: feat2 = h @ W2 (50000x128 @ 128x64) ----------------
__global__ __launch_bounds__(256) void gemm2_k(const float* __restrict__ hin,
                                               const float* __restrict__ W2,
                                               float* __restrict__ feat2) {
  __shared__ float w2s[HID * OUTF];   // 32 KB
  __shared__ float hs[16][HID];       // 8 KB
  int t = threadIdx.x;
  for (int i = t; i < HID * OUTF; i += 256) w2s[i] = W2[i];
  int c = t & 63;
  int g = t >> 6;                      // wave id 0..3 -> nodes g*4..g*4+3
  for (int chunk = blockIdx.x; chunk < NN / 16; chunk += gridDim.x) {
    int n0 = chunk * 16;
    __syncthreads();
    for (int i = t; i < 16 * HID; i += 256) {
      int r = i >> 7, k = i & 127;
      hs[r][k] = hin[(n0 + r) * HID + k];
    }
    __syncthreads();
    float a0 = 0.f, a1 = 0.f, a2 = 0.f, a3 = 0.f;
    for (int k = 0; k < HID; ++k) {
      float w = w2s[k * OUTF + c];
      a0 += hs[g * 4 + 0][k] * w;
      a1 += hs[g * 4 + 1][k] * w;
      a2 += hs[g * 4 + 2][k] * w;
      a3 += hs[g * 4 + 3][k] * w;
    }
    feat2[(n0 + g * 4 + 0) * OUTF + c] = a0;
    feat2[(n0 + g * 4 + 1) * OUTF + c] = a1;
    feat2[(n0 + g * 4 + 2) * OUTF + c] = a2;
    feat2[(n0 + g * 4 + 3) * OUTF + c] = a3;
  }
}

// ---------------- attention scores layer 2: el2/er2 [N] ----------------
__global__ __launch_bounds__(256) void scores2_k(const float* __restrict__ feat2,
                                                 const float* __restrict__ al2,
                                                 const float* __restrict__ ar2,
                                                 float* __restrict__ el2,
                                                 float* __restrict__ er2) {
  int wid = threadIdx.x >> 6, lane = threadIdx.x & 63;
  int n = blockIdx.x * 4 + wid;
  float f = feat2[n * OUTF + lane];
  float pe = f * al2[lane];
  float pr = f * ar2[lane];
#pragma unroll
  for (int off = 1; off < 64; off <<= 1) {
    pe += __shfl_xor(pe, off);
    pr += __shfl_xor(pr, off);
  }
  if (lane == 0) { el2[n] = pe; er2[n] = pr; }
}

// ---------------- layer-2 softmax + aggregation ----------------
__global__ __launch_bounds__(256) void agg2_k(const float* __restrict__ feat2,
                                              const float* __restrict__ el2,
                                              const float* __restrict__ er2,
                                              const float* __restrict__ b2,
                                              const int* __restrict__ counts,
                                              const int* __restrict__ bucket,
                                              float* __restrict__ out) {
  __shared__ float ee[4][CAP];
  int wid = threadIdx.x >> 6, lane = threadIdx.x & 63;
  int n = blockIdx.x * 4 + wid;
  int deg = counts[n]; if (deg > CAP) deg = CAP;
  float er = er2[n];

  float mx = -INFINITY;
  for (int j = lane; j < deg; j += 64) {
    int s = bucket[n * CAP + j];
    mx = fmaxf(mx, lrelu(el2[s] + er));
  }
#pragma unroll
  for (int off = 1; off < 64; off <<= 1) mx = fmaxf(mx, __shfl_xor(mx, off));
  float zs = 0.f;
  for (int j = lane; j < deg; j += 64) {
    int s = bucket[n * CAP + j];
    float ex = __expf(lrelu(el2[s] + er) - mx);
    ee[wid][j] = ex;
    zs += ex;
  }
#pragma unroll
  for (int off = 1; off < 64; off <<= 1) zs += __shfl_xor(zs, off);
  __syncthreads();
  float iz = (deg > 0) ? 1.0f / zs : 0.f;
  float acc = 0.f;
  const int base = n * CAP;
  for (int j = 0; j < deg; ++j) {
    int s = bucket[base + j];
    acc += feat2[s * OUTF + lane] * (ee[wid][j] * iz);
  }
  out[n * OUTF + lane] = acc + b2[lane];
}

extern "C" void kernel_launch(void* const* d_in, const int* in_sizes, int n_in,
                              void* d_out, int out_size, void* d_ws, size_t ws_size,
                              hipStream_t stream) {
  const float* x   = (const float*)d_in[0];
  const float* W1  = (const float*)d_in[1];
  const float* al1 = (const float*)d_in[2];
  const float* ar1 = (const float*)d_in[3];
  const float* b1  = (const float*)d_in[4];
  const float* W2  = (const float*)d_in[5];
  const float* al2 = (const float*)d_in[6];
  const float* ar2 = (const float*)d_in[7];
  const float* b2  = (const float*)d_in[8];
  const int*   src = (const int*)d_in[9];
  const int*   dst = (const int*)d_in[10];
  float* out = (float*)d_out;

  float* ws    = (float*)d_ws;
  float* feat1 = ws;                        // N*128
  float* hbuf  = feat1 + NN * HID;          // N*128
  float* el1   = hbuf + NN * HID;           // N*4
  float* er1   = el1 + NN * 4;              // N*4
  float* el2   = er1 + NN * 4;              // N
  float* er2   = el2 + NN;                  // N
  int*   counts = (int*)(er2 + NN);         // N
  int*   bucket = counts + NN;              // N*CAP
  float* feat2 = feat1;                     // reuse (feat1 dead after agg1)

  hipMemsetAsync(counts, 0, NN * sizeof(int), stream);
  gemm1_k  <<<(NN + 63) / 64, 256, 0, stream>>>(x, W1, feat1);
  scores1_k<<<NN / 4, 256, 0, stream>>>(feat1, al1, ar1, el1, er1);
  scatter_k<<<EE / 256, 256, 0, stream>>>(src, dst, counts, bucket);
  agg1_k   <<<NN / 4, 256, 0, stream>>>(feat1, el1, er1, b1, counts, bucket, hbuf);
  gemm2_k  <<<256, 256, 0, stream>>>(hbuf, W2, feat2);
  scores2_k<<<NN / 4, 256, 0, stream>>>(feat2, al2, ar2, el2, er2);
  agg2_k   <<<NN / 4, 256, 0, stream>>>(feat2, el2, er2, b2, counts, bucket, out);
}

// Round 2
// 244.424 us; speedup vs baseline: 1.2470x; 1.2470x over previous
//
#include <hip/hip_runtime.h>
#include <math.h>

#define NN   50000
#define EE   800000
#define INF_ 256
#define HID  128
#define OUTF 64
#define CAP  96
#define SLOPE 0.2f

typedef __attribute__((ext_vector_type(8))) short short8v;
typedef __attribute__((ext_vector_type(4))) float f32x4;

__device__ __forceinline__ float lrelu(float x) { return x > 0.f ? x : SLOPE * x; }
__device__ __forceinline__ float4 lrelu4(float4 v) {
  v.x = lrelu(v.x); v.y = lrelu(v.y); v.z = lrelu(v.z); v.w = lrelu(v.w); return v;
}
__device__ __forceinline__ unsigned short f2bf(float x) {
  unsigned int u = __float_as_uint(x);
  unsigned int r = (u + 0x7FFFu + ((u >> 16) & 1u)) >> 16;
  return (unsigned short)r;
}

// ---------------- convert W1 -> W1^T bf16 [128 cols][256 k] ----------------
__global__ __launch_bounds__(256) void convW1_k(const float* __restrict__ W1,
                                                unsigned short* __restrict__ W1T) {
  int id = blockIdx.x * 256 + threadIdx.x;       // 0..32767
  int k = id >> 7, c = id & 127;                 // read coalesced over c
  W1T[c * 256 + k] = f2bf(W1[k * 128 + c]);
}

// ---------------- GEMM1 (MFMA bf16): feat1 = x @ W1, fp32 out ----------------
// block: 256 thr / 4 waves; tile 64 rows x 128 cols; K chunked 2x128.
__global__ __launch_bounds__(256) void gemm1_mfma(const float* __restrict__ x,
                                                  const unsigned short* __restrict__ W1T,
                                                  float* __restrict__ feat) {
  __shared__ unsigned short As[64 * 128];   // 16 KB, swizzled
  __shared__ unsigned short Bs[128 * 128];  // 32 KB, swizzled (B^T: [col][k])
  int t = threadIdx.x;
  int lane = t & 63, wid = t >> 6;
  int n0 = blockIdx.x * 64;
  int wr = (wid >> 1) * 32;   // wave row base
  int wc = (wid & 1) * 64;    // wave col base

  f32x4 acc[2][4];
#pragma unroll
  for (int m = 0; m < 2; ++m)
#pragma unroll
    for (int n = 0; n < 4; ++n) acc[m][n] = (f32x4){0.f, 0.f, 0.f, 0.f};

  for (int pass = 0; pass < 2; ++pass) {
    int k0 = pass * 128;
    // stage A: 64 rows x 128 fp32 -> bf16, coalesced global read
#pragma unroll
    for (int it = 0; it < 8; ++it) {
      int f = it * 256 + t;          // float4 id, 0..2047
      int row = f >> 5;              // 0..63
      int c4  = f & 31;
      int grow = n0 + row;
      float4 v = make_float4(0.f, 0.f, 0.f, 0.f);
      if (grow < NN) v = *(const float4*)&x[grow * INF_ + k0 + c4 * 4];
      ushort4 b4;
      b4.x = f2bf(v.x); b4.y = f2bf(v.y); b4.z = f2bf(v.z); b4.w = f2bf(v.w);
      int byte = row * 256 + c4 * 8;
      byte ^= (row & 15) << 4;
      *(ushort4*)((char*)As + byte) = b4;
    }
    // stage B: 128 cols x 128 k bf16 from pre-converted W1T
#pragma unroll
    for (int it = 0; it < 8; ++it) {
      int f = it * 256 + t;          // ushort8 id, 0..2047
      int c  = f >> 4;               // 0..127
      int k8 = f & 15;
      uint4 v = *(const uint4*)&W1T[c * 256 + k0 + k8 * 8];
      int byte = c * 256 + k8 * 16;
      byte ^= (c & 15) << 4;
      *(uint4*)((char*)Bs + byte) = v;
    }
    __syncthreads();
#pragma unroll
    for (int ks = 0; ks < 4; ++ks) {
      int kb = ks * 64 + (lane >> 4) * 16;   // byte offset of this lane's k-slice
      short8v a[2], b[4];
#pragma unroll
      for (int m = 0; m < 2; ++m) {
        int row = wr + m * 16 + (lane & 15);
        int byte = (row * 256 + kb) ^ ((row & 15) << 4);
        a[m] = *(const short8v*)((const char*)As + byte);
      }
#pragma unroll
      for (int n = 0; n < 4; ++n) {
        int c = wc + n * 16 + (lane & 15);
        int byte = (c * 256 + kb) ^ ((c & 15) << 4);
        b[n] = *(const short8v*)((const char*)Bs + byte);
      }
#pragma unroll
      for (int m = 0; m < 2; ++m)
#pragma unroll
        for (int n = 0; n < 4; ++n)
          acc[m][n] = __builtin_amdgcn_mfma_f32_16x16x32_bf16(a[m], b[n], acc[m][n], 0, 0, 0);
    }
    __syncthreads();
  }
  // epilogue: C/D layout col=lane&15, row=(lane>>4)*4+reg
#pragma unroll
  for (int m = 0; m < 2; ++m) {
    int rbase = n0 + wr + m * 16 + (lane >> 4) * 4;
#pragma unroll
    for (int r = 0; r < 4; ++r) {
      int grow = rbase + r;
      if (grow >= NN) continue;
#pragma unroll
      for (int n = 0; n < 4; ++n) {
        int col = wc + n * 16 + (lane & 15);
        feat[grow * HID + col] = acc[m][n][r];
      }
    }
  }
}

// ---------------- attention scores layer 1: el/er [N,4] ----------------
__global__ __launch_bounds__(256) void scores1_k(const float* __restrict__ feat1,
                                                 const float* __restrict__ al,
                                                 const float* __restrict__ ar,
                                                 float* __restrict__ el,
                                                 float* __restrict__ er) {
  int wid = threadIdx.x >> 6, lane = threadIdx.x & 63;
  int n = blockIdx.x * 4 + wid;
  float f0 = feat1[n * HID + lane];
  float f1 = feat1[n * HID + 64 + lane];
  float pe0 = f0 * al[lane],      pe1 = f1 * al[64 + lane];
  float pr0 = f0 * ar[lane],      pr1 = f1 * ar[64 + lane];
#pragma unroll
  for (int off = 1; off < 32; off <<= 1) {
    pe0 += __shfl_xor(pe0, off); pe1 += __shfl_xor(pe1, off);
    pr0 += __shfl_xor(pr0, off); pr1 += __shfl_xor(pr1, off);
  }
  if ((lane & 31) == 0) {
    int hh = lane >> 5;
    el[n * 4 + hh]     = pe0;  el[n * 4 + 2 + hh] = pe1;
    er[n * 4 + hh]     = pr0;  er[n * 4 + 2 + hh] = pr1;
  }
}

// ---------------- scatter edges into per-dst buckets ----------------
__global__ __launch_bounds__(256) void scatter_k(const int* __restrict__ src,
                                                 const int* __restrict__ dst,
                                                 int* __restrict__ counts,
                                                 int* __restrict__ bucket) {
  int i = blockIdx.x * blockDim.x + threadIdx.x;
  if (i >= EE) return;
  int d = dst[i];
  int s = src[i];
  int pos = atomicAdd(&counts[d], 1);
  if (pos < CAP) bucket[d * CAP + pos] = s;
}

// ---------------- layer-1 softmax + aggregation, one wave per node ----------------
__global__ __launch_bounds__(256) void agg1_k(const float* __restrict__ feat1,
                                              const float* __restrict__ el1,
                                              const float* __restrict__ er1,
                                              const float* __restrict__ b1,
                                              const int* __restrict__ counts,
                                              const int* __restrict__ bucket,
                                              float* __restrict__ hout) {
  __shared__ float ee[4][CAP * 4];
  int wid = threadIdx.x >> 6, lane = threadIdx.x & 63;
  int n = blockIdx.x * 4 + wid;
  int deg = counts[n]; if (deg > CAP) deg = CAP;
  float4 er = *(const float4*)(er1 + n * 4);

  float4 mx = make_float4(-INFINITY, -INFINITY, -INFINITY, -INFINITY);
  for (int j = lane; j < deg; j += 64) {
    int s = bucket[n * CAP + j];
    float4 e4 = *(const float4*)(el1 + s * 4);
    float4 sc = lrelu4(make_float4(e4.x + er.x, e4.y + er.y, e4.z + er.z, e4.w + er.w));
    mx.x = fmaxf(mx.x, sc.x); mx.y = fmaxf(mx.y, sc.y);
    mx.z = fmaxf(mx.z, sc.z); mx.w = fmaxf(mx.w, sc.w);
  }
#pragma unroll
  for (int off = 1; off < 64; off <<= 1) {
    mx.x = fmaxf(mx.x, __shfl_xor(mx.x, off));
    mx.y = fmaxf(mx.y, __shfl_xor(mx.y, off));
    mx.z = fmaxf(mx.z, __shfl_xor(mx.z, off));
    mx.w = fmaxf(mx.w, __shfl_xor(mx.w, off));
  }
  float4 zs = make_float4(0.f, 0.f, 0.f, 0.f);
  for (int j = lane; j < deg; j += 64) {
    int s = bucket[n * CAP + j];
    float4 e4 = *(const float4*)(el1 + s * 4);
    float4 sc = lrelu4(make_float4(e4.x + er.x, e4.y + er.y, e4.z + er.z, e4.w + er.w));
    float4 ex = make_float4(__expf(sc.x - mx.x), __expf(sc.y - mx.y),
                            __expf(sc.z - mx.z), __expf(sc.w - mx.w));
    *(float4*)&ee[wid][j * 4] = ex;
    zs.x += ex.x; zs.y += ex.y; zs.z += ex.z; zs.w += ex.w;
  }
#pragma unroll
  for (int off = 1; off < 64; off <<= 1) {
    zs.x += __shfl_xor(zs.x, off); zs.y += __shfl_xor(zs.y, off);
    zs.z += __shfl_xor(zs.z, off); zs.w += __shfl_xor(zs.w, off);
  }
  __syncthreads();
  float iz1 = 0.f, iz2 = 0.f;
  if (deg > 0) {
    iz1 = 1.0f / ((lane < 32) ? zs.x : zs.y);
    iz2 = 1.0f / ((lane < 32) ? zs.z : zs.w);
  }
  int hsel = (lane >> 5) & 1;
  float acc0 = 0.f, acc1 = 0.f;
  const int base = n * CAP;
  for (int j = 0; j < deg; ++j) {
    int s = bucket[base + j];
    float a0 = ee[wid][j * 4 + hsel] * iz1;
    float a1 = ee[wid][j * 4 + 2 + hsel] * iz2;
    acc0 += feat1[s * HID + lane] * a0;
    acc1 += feat1[s * HID + 64 + lane] * a1;
  }
  float o0 = acc0 + b1[lane];
  float o1 = acc1 + b1[64 + lane];
  hout[n * HID + lane]      = fmaxf(o0, 0.f);
  hout[n * HID + 64 + lane] = fmaxf(o1, 0.f);
}

// ---------------- GEMM2: feat2 = h @ W2 (50000x128 @ 128x64) ----------------
__global__ __launch_bounds__(256) void gemm2_k(const float* __restrict__ hin,
                                               const float* __restrict__ W2,
                                               float* __restrict__ feat2) {
  __shared__ float w2s[HID * OUTF];   // 32 KB
  __shared__ float hs[16][HID];       // 8 KB
  int t = threadIdx.x;
  for (int i = t; i < HID * OUTF; i += 256) w2s[i] = W2[i];
  int c = t & 63;
  int g = t >> 6;
  for (int chunk = blockIdx.x; chunk < NN / 16; chunk += gridDim.x) {
    int n0 = chunk * 16;
    __syncthreads();
    for (int i = t; i < 16 * HID; i += 256) {
      int r = i >> 7, k = i & 127;
      hs[r][k] = hin[(n0 + r) * HID + k];
    }
    __syncthreads();
    float a0 = 0.f, a1 = 0.f, a2 = 0.f, a3 = 0.f;
    for (int k = 0; k < HID; ++k) {
      float w = w2s[k * OUTF + c];
      a0 += hs[g * 4 + 0][k] * w;
      a1 += hs[g * 4 + 1][k] * w;
      a2 += hs[g * 4 + 2][k] * w;
      a3 += hs[g * 4 + 3][k] * w;
    }
    feat2[(n0 + g * 4 + 0) * OUTF + c] = a0;
    feat2[(n0 + g * 4 + 1) * OUTF + c] = a1;
    feat2[(n0 + g * 4 + 2) * OUTF + c] = a2;
    feat2[(n0 + g * 4 + 3) * OUTF + c] = a3;
  }
}

// ---------------- attention scores layer 2: el2/er2 [N] ----------------
__global__ __launch_bounds__(256) void scores2_k(const float* __restrict__ feat2,
                                                 const float* __restrict__ al2,
                                                 const float* __restrict__ ar2,
                                                 float* __restrict__ el2,
                                                 float* __restrict__ er2) {
  int wid = threadIdx.x >> 6, lane = threadIdx.x & 63;
  int n = blockIdx.x * 4 + wid;
  float f = feat2[n * OUTF + lane];
  float pe = f * al2[lane];
  float pr = f * ar2[lane];
#pragma unroll
  for (int off = 1; off < 64; off <<= 1) {
    pe += __shfl_xor(pe, off);
    pr += __shfl_xor(pr, off);
  }
  if (lane == 0) { el2[n] = pe; er2[n] = pr; }
}

// ---------------- layer-2 softmax + aggregation ----------------
__global__ __launch_bounds__(256) void agg2_k(const float* __restrict__ feat2,
                                              const float* __restrict__ el2,
                                              const float* __restrict__ er2,
                                              const float* __restrict__ b2,
                                              const int* __restrict__ counts,
                                              const int* __restrict__ bucket,
                                              float* __restrict__ out) {
  __shared__ float ee[4][CAP];
  int wid = threadIdx.x >> 6, lane = threadIdx.x & 63;
  int n = blockIdx.x * 4 + wid;
  int deg = counts[n]; if (deg > CAP) deg = CAP;
  float er = er2[n];

  float mx = -INFINITY;
  for (int j = lane; j < deg; j += 64) {
    int s = bucket[n * CAP + j];
    mx = fmaxf(mx, lrelu(el2[s] + er));
  }
#pragma unroll
  for (int off = 1; off < 64; off <<= 1) mx = fmaxf(mx, __shfl_xor(mx, off));
  float zs = 0.f;
  for (int j = lane; j < deg; j += 64) {
    int s = bucket[n * CAP + j];
    float ex = __expf(lrelu(el2[s] + er) - mx);
    ee[wid][j] = ex;
    zs += ex;
  }
#pragma unroll
  for (int off = 1; off < 64; off <<= 1) zs += __shfl_xor(zs, off);
  __syncthreads();
  float iz = (deg > 0) ? 1.0f / zs : 0.f;
  float acc = 0.f;
  const int base = n * CAP;
  for (int j = 0; j < deg; ++j) {
    int s = bucket[base + j];
    acc += feat2[s * OUTF + lane] * (ee[wid][j] * iz);
  }
  out[n * OUTF + lane] = acc + b2[lane];
}

extern "C" void kernel_launch(void* const* d_in, const int* in_sizes, int n_in,
                              void* d_out, int out_size, void* d_ws, size_t ws_size,
                              hipStream_t stream) {
  const float* x   = (const float*)d_in[0];
  const float* W1  = (const float*)d_in[1];
  const float* al1 = (const float*)d_in[2];
  const float* ar1 = (const float*)d_in[3];
  const float* b1  = (const float*)d_in[4];
  const float* W2  = (const float*)d_in[5];
  const float* al2 = (const float*)d_in[6];
  const float* ar2 = (const float*)d_in[7];
  const float* b2  = (const float*)d_in[8];
  const int*   src = (const int*)d_in[9];
  const int*   dst = (const int*)d_in[10];
  float* out = (float*)d_out;

  float* ws    = (float*)d_ws;
  float* feat1 = ws;                        // N*128
  float* hbuf  = feat1 + NN * HID;          // N*128
  float* el1   = hbuf + NN * HID;           // N*4
  float* er1   = el1 + NN * 4;              // N*4
  float* el2   = er1 + NN * 4;              // N
  float* er2   = el2 + NN;                  // N
  int*   counts = (int*)(er2 + NN);         // N
  int*   bucket = counts + NN;              // N*CAP
  unsigned short* W1T = (unsigned short*)(bucket + NN * CAP);  // 256*128 bf16
  float* feat2 = feat1;                     // reuse (feat1 dead after agg1)

  hipMemsetAsync(counts, 0, NN * sizeof(int), stream);
  convW1_k  <<<128, 256, 0, stream>>>(W1, W1T);
  gemm1_mfma<<<(NN + 63) / 64, 256, 0, stream>>>(x, W1T, feat1);
  scores1_k <<<NN / 4, 256, 0, stream>>>(feat1, al1, ar1, el1, er1);
  scatter_k <<<EE / 256, 256, 0, stream>>>(src, dst, counts, bucket);
  agg1_k    <<<NN / 4, 256, 0, stream>>>(feat1, el1, er1, b1, counts, bucket, hbuf);
  gemm2_k   <<<625, 256, 0, stream>>>(hbuf, W2, feat2);
  scores2_k <<<NN / 4, 256, 0, stream>>>(feat2, al2, ar2, el2, er2);
  agg2_k    <<<NN / 4, 256, 0, stream>>>(feat2, el2, er2, b2, counts, bucket, out);
}

// Round 3
// 203.892 us; speedup vs baseline: 1.4949x; 1.1988x over previous
//
#include <hip/hip_runtime.h>
#include <math.h>

#define NN   50000
#define EE   800000
#define INF_ 256
#define HID  128
#define OUTF 64
#define CAP  96
#define SLOPE 0.2f

typedef __attribute__((ext_vector_type(8))) short short8v;
typedef __attribute__((ext_vector_type(4))) float f32x4;

__device__ __forceinline__ float lrelu(float x) { return x > 0.f ? x : SLOPE * x; }
__device__ __forceinline__ float4 lrelu4(float4 v) {
  v.x = lrelu(v.x); v.y = lrelu(v.y); v.z = lrelu(v.z); v.w = lrelu(v.w); return v;
}
__device__ __forceinline__ unsigned short f2bf(float x) {
  unsigned int u = __float_as_uint(x);
  unsigned int r = (u + 0x7FFFu + ((u >> 16) & 1u)) >> 16;
  return (unsigned short)r;
}

// ---------------- convert W1 -> W1^T bf16 [128 cols][256 k] ----------------
__global__ __launch_bounds__(256) void convW1_k(const float* __restrict__ W1,
                                                unsigned short* __restrict__ W1T) {
  int id = blockIdx.x * 256 + threadIdx.x;       // 0..32767
  int k = id >> 7, c = id & 127;
  W1T[c * 256 + k] = f2bf(W1[k * 128 + c]);
}

// ---------------- convert W2 -> W2^T bf16 [64 cols][128 k] ----------------
__global__ __launch_bounds__(256) void convW2_k(const float* __restrict__ W2,
                                                unsigned short* __restrict__ W2T) {
  int id = blockIdx.x * 256 + threadIdx.x;       // 0..8191
  int k = id >> 6, c = id & 63;
  W2T[c * 128 + k] = f2bf(W2[id]);
}

// ---------------- GEMM1 (MFMA bf16): feat1b = bf16(x @ W1) ----------------
__global__ __launch_bounds__(256) void gemm1_mfma(const float* __restrict__ x,
                                                  const unsigned short* __restrict__ W1T,
                                                  unsigned short* __restrict__ featb) {
  __shared__ unsigned short As[64 * 128];   // 16 KB, swizzled (also epilogue staging)
  __shared__ unsigned short Bs[128 * 128];  // 32 KB, swizzled (B^T: [col][k])
  int t = threadIdx.x;
  int lane = t & 63, wid = t >> 6;
  int n0 = blockIdx.x * 64;
  int wr = (wid >> 1) * 32;   // wave row base
  int wc = (wid & 1) * 64;    // wave col base

  f32x4 acc[2][4];
#pragma unroll
  for (int m = 0; m < 2; ++m)
#pragma unroll
    for (int n = 0; n < 4; ++n) acc[m][n] = (f32x4){0.f, 0.f, 0.f, 0.f};

  for (int pass = 0; pass < 2; ++pass) {
    int k0 = pass * 128;
#pragma unroll
    for (int it = 0; it < 8; ++it) {
      int f = it * 256 + t;
      int row = f >> 5;
      int c4  = f & 31;
      int grow = n0 + row;
      float4 v = make_float4(0.f, 0.f, 0.f, 0.f);
      if (grow < NN) v = *(const float4*)&x[grow * INF_ + k0 + c4 * 4];
      ushort4 b4;
      b4.x = f2bf(v.x); b4.y = f2bf(v.y); b4.z = f2bf(v.z); b4.w = f2bf(v.w);
      int byte = row * 256 + c4 * 8;
      byte ^= (row & 15) << 4;
      *(ushort4*)((char*)As + byte) = b4;
    }
#pragma unroll
    for (int it = 0; it < 8; ++it) {
      int f = it * 256 + t;
      int c  = f >> 4;
      int k8 = f & 15;
      uint4 v = *(const uint4*)&W1T[c * 256 + k0 + k8 * 8];
      int byte = c * 256 + k8 * 16;
      byte ^= (c & 15) << 4;
      *(uint4*)((char*)Bs + byte) = v;
    }
    __syncthreads();
#pragma unroll
    for (int ks = 0; ks < 4; ++ks) {
      int kb = ks * 64 + (lane >> 4) * 16;
      short8v a[2], b[4];
#pragma unroll
      for (int m = 0; m < 2; ++m) {
        int row = wr + m * 16 + (lane & 15);
        int byte = (row * 256 + kb) ^ ((row & 15) << 4);
        a[m] = *(const short8v*)((const char*)As + byte);
      }
#pragma unroll
      for (int n = 0; n < 4; ++n) {
        int c = wc + n * 16 + (lane & 15);
        int byte = (c * 256 + kb) ^ ((c & 15) << 4);
        b[n] = *(const short8v*)((const char*)Bs + byte);
      }
#pragma unroll
      for (int m = 0; m < 2; ++m)
#pragma unroll
        for (int n = 0; n < 4; ++n)
          acc[m][n] = __builtin_amdgcn_mfma_f32_16x16x32_bf16(a[m], b[n], acc[m][n], 0, 0, 0);
    }
    __syncthreads();
  }
  // epilogue: stage bf16 tile in LDS (reuse As), then coalesced write
#pragma unroll
  for (int m = 0; m < 2; ++m) {
    int rbase = wr + m * 16 + (lane >> 4) * 4;
#pragma unroll
    for (int r = 0; r < 4; ++r)
#pragma unroll
      for (int n = 0; n < 4; ++n)
        As[(rbase + r) * 128 + wc + n * 16 + (lane & 15)] = f2bf(acc[m][n][r]);
  }
  __syncthreads();
#pragma unroll
  for (int it = 0; it < 4; ++it) {
    int id = it * 256 + t;            // uint4 id, 0..1023
    int row = id >> 4, c8 = id & 15;
    int grow = n0 + row;
    if (grow < NN)
      *(uint4*)&featb[grow * HID + c8 * 8] = *(const uint4*)&As[row * 128 + c8 * 8];
  }
}

// ---------------- attention scores layer 1 (bf16 feat): el/er [N,4] ----------------
__global__ __launch_bounds__(256) void scores1_k(const unsigned short* __restrict__ featb,
                                                 const float* __restrict__ al,
                                                 const float* __restrict__ ar,
                                                 float* __restrict__ el,
                                                 float* __restrict__ er) {
  int wid = threadIdx.x >> 6, lane = threadIdx.x & 63;
  int n = blockIdx.x * 4 + wid;
  unsigned int u = *(const unsigned int*)&featb[n * HID + lane * 2];
  float f0 = __uint_as_float(u << 16);
  float f1 = __uint_as_float(u & 0xFFFF0000u);
  int c0 = lane * 2;
  float pe = f0 * al[c0] + f1 * al[c0 + 1];
  float pr = f0 * ar[c0] + f1 * ar[c0 + 1];
#pragma unroll
  for (int off = 1; off < 16; off <<= 1) {
    pe += __shfl_xor(pe, off);
    pr += __shfl_xor(pr, off);
  }
  if ((lane & 15) == 0) {
    int hh = lane >> 4;
    el[n * 4 + hh] = pe;
    er[n * 4 + hh] = pr;
  }
}

// ---------------- scatter edges into per-dst buckets ----------------
__global__ __launch_bounds__(256) void scatter_k(const int* __restrict__ src,
                                                 const int* __restrict__ dst,
                                                 int* __restrict__ counts,
                                                 int* __restrict__ bucket) {
  int i = blockIdx.x * blockDim.x + threadIdx.x;
  if (i >= EE) return;
  int d = dst[i];
  int s = src[i];
  int pos = atomicAdd(&counts[d], 1);
  if (pos < CAP) bucket[d * CAP + pos] = s;
}

// ---------------- layer-1 softmax + aggregation (bf16 gathers) ----------------
__global__ __launch_bounds__(256) void agg1_k(const unsigned short* __restrict__ featb,
                                              const float* __restrict__ el1,
                                              const float* __restrict__ er1,
                                              const float* __restrict__ b1,
                                              const int* __restrict__ counts,
                                              const int* __restrict__ bucket,
                                              unsigned short* __restrict__ houtb) {
  __shared__ float ee[4][CAP * 4];
  int wid = threadIdx.x >> 6, lane = threadIdx.x & 63;
  int n = blockIdx.x * 4 + wid;
  int deg = counts[n]; if (deg > CAP) deg = CAP;
  float4 er = *(const float4*)(er1 + n * 4);

  float4 mx = make_float4(-INFINITY, -INFINITY, -INFINITY, -INFINITY);
  for (int j = lane; j < deg; j += 64) {
    int s = bucket[n * CAP + j];
    float4 e4 = *(const float4*)(el1 + s * 4);
    float4 sc = lrelu4(make_float4(e4.x + er.x, e4.y + er.y, e4.z + er.z, e4.w + er.w));
    mx.x = fmaxf(mx.x, sc.x); mx.y = fmaxf(mx.y, sc.y);
    mx.z = fmaxf(mx.z, sc.z); mx.w = fmaxf(mx.w, sc.w);
  }
#pragma unroll
  for (int off = 1; off < 64; off <<= 1) {
    mx.x = fmaxf(mx.x, __shfl_xor(mx.x, off));
    mx.y = fmaxf(mx.y, __shfl_xor(mx.y, off));
    mx.z = fmaxf(mx.z, __shfl_xor(mx.z, off));
    mx.w = fmaxf(mx.w, __shfl_xor(mx.w, off));
  }
  float4 zs = make_float4(0.f, 0.f, 0.f, 0.f);
  for (int j = lane; j < deg; j += 64) {
    int s = bucket[n * CAP + j];
    float4 e4 = *(const float4*)(el1 + s * 4);
    float4 sc = lrelu4(make_float4(e4.x + er.x, e4.y + er.y, e4.z + er.z, e4.w + er.w));
    float4 ex = make_float4(__expf(sc.x - mx.x), __expf(sc.y - mx.y),
                            __expf(sc.z - mx.z), __expf(sc.w - mx.w));
    *(float4*)&ee[wid][j * 4] = ex;
    zs.x += ex.x; zs.y += ex.y; zs.z += ex.z; zs.w += ex.w;
  }
#pragma unroll
  for (int off = 1; off < 64; off <<= 1) {
    zs.x += __shfl_xor(zs.x, off); zs.y += __shfl_xor(zs.y, off);
    zs.z += __shfl_xor(zs.z, off); zs.w += __shfl_xor(zs.w, off);
  }
  __syncthreads();
  int hl = lane >> 4;            // head for channels 2*lane, 2*lane+1
  float zsel = (hl & 2) ? ((hl & 1) ? zs.w : zs.z) : ((hl & 1) ? zs.y : zs.x);
  float iz = (deg > 0) ? 1.0f / zsel : 0.f;
  float acc0 = 0.f, acc1 = 0.f;
  const int base = n * CAP;
  for (int j = 0; j < deg; ++j) {
    int s = bucket[base + j];
    float w = ee[wid][j * 4 + hl] * iz;
    unsigned int u = *(const unsigned int*)&featb[s * HID + lane * 2];
    float f0 = __uint_as_float(u << 16);
    float f1 = __uint_as_float(u & 0xFFFF0000u);
    acc0 += f0 * w; acc1 += f1 * w;
  }
  float2 bb = *(const float2*)&b1[lane * 2];
  float o0 = fmaxf(acc0 + bb.x, 0.f);
  float o1 = fmaxf(acc1 + bb.y, 0.f);
  unsigned int p = (unsigned int)f2bf(o0) | ((unsigned int)f2bf(o1) << 16);
  *(unsigned int*)&houtb[n * HID + lane * 2] = p;
}

// ---------------- GEMM2 (MFMA bf16): feat2 = h @ W2, fp32 out ----------------
__global__ __launch_bounds__(256) void gemm2_mfma(const unsigned short* __restrict__ hb,
                                                  const unsigned short* __restrict__ W2T,
                                                  float* __restrict__ feat2) {
  __shared__ unsigned short As[64 * 128];  // 16 KB swizzled
  __shared__ unsigned short Bs[64 * 128];  // 16 KB swizzled
  int t = threadIdx.x, lane = t & 63, wid = t >> 6;
  int n0 = blockIdx.x * 64;
  f32x4 acc[4];
#pragma unroll
  for (int n = 0; n < 4; ++n) acc[n] = (f32x4){0.f, 0.f, 0.f, 0.f};

#pragma unroll
  for (int it = 0; it < 4; ++it) {
    int id = it * 256 + t;
    int row = id >> 4, c8 = id & 15;
    int grow = n0 + row;
    uint4 v = make_uint4(0, 0, 0, 0);
    if (grow < NN) v = *(const uint4*)&hb[grow * HID + c8 * 8];
    int byte = row * 256 + c8 * 16;
    byte ^= (row & 15) << 4;
    *(uint4*)((char*)As + byte) = v;
  }
#pragma unroll
  for (int it = 0; it < 4; ++it) {
    int id = it * 256 + t;
    int row = id >> 4, c8 = id & 15;   // row = col of W2 (0..63)
    uint4 v = *(const uint4*)&W2T[row * 128 + c8 * 8];
    int byte = row * 256 + c8 * 16;
    byte ^= (row & 15) << 4;
    *(uint4*)((char*)Bs + byte) = v;
  }
  __syncthreads();
  int wr = wid * 16;
#pragma unroll
  for (int ks = 0; ks < 4; ++ks) {
    int kb = ks * 64 + (lane >> 4) * 16;
    int arow = wr + (lane & 15);
    int abyte = (arow * 256 + kb) ^ ((arow & 15) << 4);
    short8v a = *(const short8v*)((const char*)As + abyte);
#pragma unroll
    for (int n = 0; n < 4; ++n) {
      int c = n * 16 + (lane & 15);
      int bbyte = (c * 256 + kb) ^ ((c & 15) << 4);
      short8v b = *(const short8v*)((const char*)Bs + bbyte);
      acc[n] = __builtin_amdgcn_mfma_f32_16x16x32_bf16(a, b, acc[n], 0, 0, 0);
    }
  }
  int rbase = n0 + wr + (lane >> 4) * 4;
#pragma unroll
  for (int r = 0; r < 4; ++r) {
    int grow = rbase + r;
    if (grow >= NN) continue;
#pragma unroll
    for (int n = 0; n < 4; ++n)
      feat2[grow * OUTF + n * 16 + (lane & 15)] = acc[n][r];
  }
}

// ---------------- attention scores layer 2: el2/er2 [N] ----------------
__global__ __launch_bounds__(256) void scores2_k(const float* __restrict__ feat2,
                                                 const float* __restrict__ al2,
                                                 const float* __restrict__ ar2,
                                                 float* __restrict__ el2,
                                                 float* __restrict__ er2) {
  int wid = threadIdx.x >> 6, lane = threadIdx.x & 63;
  int n = blockIdx.x * 4 + wid;
  float f = feat2[n * OUTF + lane];
  float pe = f * al2[lane];
  float pr = f * ar2[lane];
#pragma unroll
  for (int off = 1; off < 64; off <<= 1) {
    pe += __shfl_xor(pe, off);
    pr += __shfl_xor(pr, off);
  }
  if (lane == 0) { el2[n] = pe; er2[n] = pr; }
}

// ---------------- layer-2 softmax + aggregation ----------------
__global__ __launch_bounds__(256) void agg2_k(const float* __restrict__ feat2,
                                              const float* __restrict__ el2,
                                              const float* __restrict__ er2,
                                              const float* __restrict__ b2,
                                              const int* __restrict__ counts,
                                              const int* __restrict__ bucket,
                                              float* __restrict__ out) {
  __shared__ float ee[4][CAP];
  int wid = threadIdx.x >> 6, lane = threadIdx.x & 63;
  int n = blockIdx.x * 4 + wid;
  int deg = counts[n]; if (deg > CAP) deg = CAP;
  float er = er2[n];

  float mx = -INFINITY;
  for (int j = lane; j < deg; j += 64) {
    int s = bucket[n * CAP + j];
    mx = fmaxf(mx, lrelu(el2[s] + er));
  }
#pragma unroll
  for (int off = 1; off < 64; off <<= 1) mx = fmaxf(mx, __shfl_xor(mx, off));
  float zs = 0.f;
  for (int j = lane; j < deg; j += 64) {
    int s = bucket[n * CAP + j];
    float ex = __expf(lrelu(el2[s] + er) - mx);
    ee[wid][j] = ex;
    zs += ex;
  }
#pragma unroll
  for (int off = 1; off < 64; off <<= 1) zs += __shfl_xor(zs, off);
  __syncthreads();
  float iz = (deg > 0) ? 1.0f / zs : 0.f;
  float acc = 0.f;
  const int base = n * CAP;
  for (int j = 0; j < deg; ++j) {
    int s = bucket[base + j];
    acc += feat2[s * OUTF + lane] * (ee[wid][j] * iz);
  }
  out[n * OUTF + lane] = acc + b2[lane];
}

extern "C" void kernel_launch(void* const* d_in, const int* in_sizes, int n_in,
                              void* d_out, int out_size, void* d_ws, size_t ws_size,
                              hipStream_t stream) {
  const float* x   = (const float*)d_in[0];
  const float* W1  = (const float*)d_in[1];
  const float* al1 = (const float*)d_in[2];
  const float* ar1 = (const float*)d_in[3];
  const float* b1  = (const float*)d_in[4];
  const float* W2  = (const float*)d_in[5];
  const float* al2 = (const float*)d_in[6];
  const float* ar2 = (const float*)d_in[7];
  const float* b2  = (const float*)d_in[8];
  const int*   src = (const int*)d_in[9];
  const int*   dst = (const int*)d_in[10];
  float* out = (float*)d_out;

  char* base = (char*)d_ws;
  unsigned short* feat1b = (unsigned short*)base;                 // N*128 bf16 (12.8 MB)
  float*          feat2  = (float*)base;                          // overlay: N*64 fp32 (12.8 MB)
  unsigned short* hb     = (unsigned short*)(base + 12800000);    // N*128 bf16
  float* el1 = (float*)(base + 25600000);                         // N*4
  float* er1 = el1 + NN * 4;                                      // N*4
  float* el2 = er1 + NN * 4;                                      // N
  float* er2 = el2 + NN;                                          // N
  int* counts = (int*)(er2 + NN);                                 // N
  int* bucket = counts + NN;                                      // N*CAP
  unsigned short* W1T = (unsigned short*)(bucket + NN * CAP);     // 256*128
  unsigned short* W2T = W1T + 256 * 128;                          // 64*128

  hipMemsetAsync(counts, 0, NN * sizeof(int), stream);
  convW1_k  <<<128, 256, 0, stream>>>(W1, W1T);
  convW2_k  <<<32, 256, 0, stream>>>(W2, W2T);
  gemm1_mfma<<<(NN + 63) / 64, 256, 0, stream>>>(x, W1T, feat1b);
  scores1_k <<<NN / 4, 256, 0, stream>>>(feat1b, al1, ar1, el1, er1);
  scatter_k <<<EE / 256, 256, 0, stream>>>(src, dst, counts, bucket);
  agg1_k    <<<NN / 4, 256, 0, stream>>>(feat1b, el1, er1, b1, counts, bucket, hb);
  gemm2_mfma<<<(NN + 63) / 64, 256, 0, stream>>>(hb, W2T, feat2);
  scores2_k <<<NN / 4, 256, 0, stream>>>(feat2, al2, ar2, el2, er2);
  agg2_k    <<<NN / 4, 256, 0, stream>>>(feat2, el2, er2, b2, counts, bucket, out);
}

// Round 4
// 181.476 us; speedup vs baseline: 1.6796x; 1.1235x over previous
//
#include <hip/hip_runtime.h>
#include <math.h>

#define NN   50000
#define EE   800000
#define INF_ 256
#define HID  128
#define OUTF 64
#define CAP  96
#define SLOPE 0.2f

typedef __attribute__((ext_vector_type(8))) short short8v;
typedef __attribute__((ext_vector_type(4))) float f32x4;

__device__ __forceinline__ float lrelu(float x) { return x > 0.f ? x : SLOPE * x; }
__device__ __forceinline__ float4 lrelu4(float4 v) {
  v.x = lrelu(v.x); v.y = lrelu(v.y); v.z = lrelu(v.z); v.w = lrelu(v.w); return v;
}
__device__ __forceinline__ unsigned short f2bf(float x) {
  unsigned int u = __float_as_uint(x);
  unsigned int r = (u + 0x7FFFu + ((u >> 16) & 1u)) >> 16;
  return (unsigned short)r;
}

// ---------------- convert W1 -> W1^T bf16 [128 cols][256 k] ----------------
__global__ __launch_bounds__(256) void convW1_k(const float* __restrict__ W1,
                                                unsigned short* __restrict__ W1T) {
  int id = blockIdx.x * 256 + threadIdx.x;
  int k = id >> 7, c = id & 127;
  W1T[c * 256 + k] = f2bf(W1[k * 128 + c]);
}

// ---------------- convert W2 -> W2^T bf16 [64 cols][128 k] ----------------
__global__ __launch_bounds__(256) void convW2_k(const float* __restrict__ W2,
                                                unsigned short* __restrict__ W2T) {
  int id = blockIdx.x * 256 + threadIdx.x;
  int k = id >> 6, c = id & 63;
  W2T[c * 128 + k] = f2bf(W2[id]);
}

// ---------------- GEMM1 (MFMA bf16): feat1b = bf16(x @ W1) ----------------
__global__ __launch_bounds__(256) void gemm1_mfma(const float* __restrict__ x,
                                                  const unsigned short* __restrict__ W1T,
                                                  unsigned short* __restrict__ featb) {
  __shared__ unsigned short As[64 * 128];
  __shared__ unsigned short Bs[128 * 128];
  int t = threadIdx.x;
  int lane = t & 63, wid = t >> 6;
  int n0 = blockIdx.x * 64;
  int wr = (wid >> 1) * 32;
  int wc = (wid & 1) * 64;

  f32x4 acc[2][4];
#pragma unroll
  for (int m = 0; m < 2; ++m)
#pragma unroll
    for (int n = 0; n < 4; ++n) acc[m][n] = (f32x4){0.f, 0.f, 0.f, 0.f};

  for (int pass = 0; pass < 2; ++pass) {
    int k0 = pass * 128;
#pragma unroll
    for (int it = 0; it < 8; ++it) {
      int f = it * 256 + t;
      int row = f >> 5;
      int c4  = f & 31;
      int grow = n0 + row;
      float4 v = make_float4(0.f, 0.f, 0.f, 0.f);
      if (grow < NN) v = *(const float4*)&x[grow * INF_ + k0 + c4 * 4];
      ushort4 b4;
      b4.x = f2bf(v.x); b4.y = f2bf(v.y); b4.z = f2bf(v.z); b4.w = f2bf(v.w);
      int byte = row * 256 + c4 * 8;
      byte ^= (row & 15) << 4;
      *(ushort4*)((char*)As + byte) = b4;
    }
#pragma unroll
    for (int it = 0; it < 8; ++it) {
      int f = it * 256 + t;
      int c  = f >> 4;
      int k8 = f & 15;
      uint4 v = *(const uint4*)&W1T[c * 256 + k0 + k8 * 8];
      int byte = c * 256 + k8 * 16;
      byte ^= (c & 15) << 4;
      *(uint4*)((char*)Bs + byte) = v;
    }
    __syncthreads();
#pragma unroll
    for (int ks = 0; ks < 4; ++ks) {
      int kb = ks * 64 + (lane >> 4) * 16;
      short8v a[2], b[4];
#pragma unroll
      for (int m = 0; m < 2; ++m) {
        int row = wr + m * 16 + (lane & 15);
        int byte = (row * 256 + kb) ^ ((row & 15) << 4);
        a[m] = *(const short8v*)((const char*)As + byte);
      }
#pragma unroll
      for (int n = 0; n < 4; ++n) {
        int c = wc + n * 16 + (lane & 15);
        int byte = (c * 256 + kb) ^ ((c & 15) << 4);
        b[n] = *(const short8v*)((const char*)Bs + byte);
      }
#pragma unroll
      for (int m = 0; m < 2; ++m)
#pragma unroll
        for (int n = 0; n < 4; ++n)
          acc[m][n] = __builtin_amdgcn_mfma_f32_16x16x32_bf16(a[m], b[n], acc[m][n], 0, 0, 0);
    }
    __syncthreads();
  }
#pragma unroll
  for (int m = 0; m < 2; ++m) {
    int rbase = wr + m * 16 + (lane >> 4) * 4;
#pragma unroll
    for (int r = 0; r < 4; ++r)
#pragma unroll
      for (int n = 0; n < 4; ++n)
        As[(rbase + r) * 128 + wc + n * 16 + (lane & 15)] = f2bf(acc[m][n][r]);
  }
  __syncthreads();
#pragma unroll
  for (int it = 0; it < 4; ++it) {
    int id = it * 256 + t;
    int row = id >> 4, c8 = id & 15;
    int grow = n0 + row;
    if (grow < NN)
      *(uint4*)&featb[grow * HID + c8 * 8] = *(const uint4*)&As[row * 128 + c8 * 8];
  }
}

// ---------------- attention scores layer 1 (bf16 feat): el/er [N,4] ----------------
__global__ __launch_bounds__(256) void scores1_k(const unsigned short* __restrict__ featb,
                                                 const float* __restrict__ al,
                                                 const float* __restrict__ ar,
                                                 float* __restrict__ el,
                                                 float* __restrict__ er) {
  int wid = threadIdx.x >> 6, lane = threadIdx.x & 63;
  int n = blockIdx.x * 4 + wid;
  unsigned int u = *(const unsigned int*)&featb[n * HID + lane * 2];
  float f0 = __uint_as_float(u << 16);
  float f1 = __uint_as_float(u & 0xFFFF0000u);
  int c0 = lane * 2;
  float pe = f0 * al[c0] + f1 * al[c0 + 1];
  float pr = f0 * ar[c0] + f1 * ar[c0 + 1];
#pragma unroll
  for (int off = 1; off < 16; off <<= 1) {
    pe += __shfl_xor(pe, off);
    pr += __shfl_xor(pr, off);
  }
  if ((lane & 15) == 0) {
    int hh = lane >> 4;
    el[n * 4 + hh] = pe;
    er[n * 4 + hh] = pr;
  }
}

// ---------------- scatter edges into per-dst buckets (store BYTE offsets s*256) --------
__global__ __launch_bounds__(256) void scatter_k(const int* __restrict__ src,
                                                 const int* __restrict__ dst,
                                                 int* __restrict__ counts,
                                                 int* __restrict__ bucket) {
  int i = blockIdx.x * blockDim.x + threadIdx.x;
  if (i >= EE) return;
  int d = dst[i];
  int s = src[i];
  int pos = atomicAdd(&counts[d], 1);
  if (pos < CAP) bucket[d * CAP + pos] = s << 8;   // s*256 bytes
}

// ---------------- layer-1 softmax + aggregation (bf16 gathers) ----------------
__global__ __launch_bounds__(256) void agg1_k(const unsigned short* __restrict__ featb,
                                              const float* __restrict__ el1,
                                              const float* __restrict__ er1,
                                              const float* __restrict__ b1,
                                              const int* __restrict__ counts,
                                              const int* __restrict__ bucket,
                                              unsigned short* __restrict__ houtb) {
  __shared__ float ee[4][CAP * 4];
  int wid = threadIdx.x >> 6, lane = threadIdx.x & 63;
  int n = blockIdx.x * 4 + wid;
  int deg = counts[n]; if (deg > CAP) deg = CAP;
  const int* bk = bucket + n * CAP;
  float4 er = *(const float4*)(er1 + n * 4);
  int hl = lane >> 4;
  int m64 = deg < 64 ? deg : 64;
  int myoff = (lane < m64) ? bk[lane] : -1;

  if (deg <= 64) {
    // single-pass: lane j owns edge j
    float4 sc = make_float4(-INFINITY, -INFINITY, -INFINITY, -INFINITY);
    if (myoff >= 0) {
      float4 e4 = *(const float4*)((const char*)el1 + (myoff >> 4));
      sc = lrelu4(make_float4(e4.x + er.x, e4.y + er.y, e4.z + er.z, e4.w + er.w));
    }
    float4 mx = sc;
#pragma unroll
    for (int off = 1; off < 64; off <<= 1) {
      mx.x = fmaxf(mx.x, __shfl_xor(mx.x, off));
      mx.y = fmaxf(mx.y, __shfl_xor(mx.y, off));
      mx.z = fmaxf(mx.z, __shfl_xor(mx.z, off));
      mx.w = fmaxf(mx.w, __shfl_xor(mx.w, off));
    }
    float4 ex = make_float4(0.f, 0.f, 0.f, 0.f);
    if (myoff >= 0)
      ex = make_float4(__expf(sc.x - mx.x), __expf(sc.y - mx.y),
                       __expf(sc.z - mx.z), __expf(sc.w - mx.w));
    float4 zs = ex;
#pragma unroll
    for (int off = 1; off < 64; off <<= 1) {
      zs.x += __shfl_xor(zs.x, off); zs.y += __shfl_xor(zs.y, off);
      zs.z += __shfl_xor(zs.z, off); zs.w += __shfl_xor(zs.w, off);
    }
    if (myoff >= 0) {
      float4 w = make_float4(ex.x / zs.x, ex.y / zs.y, ex.z / zs.z, ex.w / zs.w);
      *(float4*)&ee[wid][lane * 4] = w;
    }
  } else {
    // rare: deg in (64, CAP]
    float4 mx = make_float4(-INFINITY, -INFINITY, -INFINITY, -INFINITY);
    for (int j = lane; j < deg; j += 64) {
      int o = bk[j];
      float4 e4 = *(const float4*)((const char*)el1 + (o >> 4));
      float4 sc = lrelu4(make_float4(e4.x + er.x, e4.y + er.y, e4.z + er.z, e4.w + er.w));
      mx.x = fmaxf(mx.x, sc.x); mx.y = fmaxf(mx.y, sc.y);
      mx.z = fmaxf(mx.z, sc.z); mx.w = fmaxf(mx.w, sc.w);
    }
#pragma unroll
    for (int off = 1; off < 64; off <<= 1) {
      mx.x = fmaxf(mx.x, __shfl_xor(mx.x, off));
      mx.y = fmaxf(mx.y, __shfl_xor(mx.y, off));
      mx.z = fmaxf(mx.z, __shfl_xor(mx.z, off));
      mx.w = fmaxf(mx.w, __shfl_xor(mx.w, off));
    }
    float4 zs = make_float4(0.f, 0.f, 0.f, 0.f);
    for (int j = lane; j < deg; j += 64) {
      int o = bk[j];
      float4 e4 = *(const float4*)((const char*)el1 + (o >> 4));
      float4 sc = lrelu4(make_float4(e4.x + er.x, e4.y + er.y, e4.z + er.z, e4.w + er.w));
      float4 ex = make_float4(__expf(sc.x - mx.x), __expf(sc.y - mx.y),
                              __expf(sc.z - mx.z), __expf(sc.w - mx.w));
      *(float4*)&ee[wid][j * 4] = ex;
      zs.x += ex.x; zs.y += ex.y; zs.z += ex.z; zs.w += ex.w;
    }
#pragma unroll
    for (int off = 1; off < 64; off <<= 1) {
      zs.x += __shfl_xor(zs.x, off); zs.y += __shfl_xor(zs.y, off);
      zs.z += __shfl_xor(zs.z, off); zs.w += __shfl_xor(zs.w, off);
    }
    float4 iz = make_float4(1.f / zs.x, 1.f / zs.y, 1.f / zs.z, 1.f / zs.w);
    for (int j = lane; j < deg; j += 64) {
      float4 t = *(const float4*)&ee[wid][j * 4];
      t.x *= iz.x; t.y *= iz.y; t.z *= iz.z; t.w *= iz.w;
      *(float4*)&ee[wid][j * 4] = t;
    }
  }

  // gather-aggregate: 4-edge unroll, offsets broadcast from registers
  float acc0 = 0.f, acc1 = 0.f;
  const char* fb = (const char*)featb;
  int lb = lane * 4;
  int j = 0;
  for (; j + 4 <= m64; j += 4) {
    int o0 = __shfl(myoff, j);
    int o1 = __shfl(myoff, j + 1);
    int o2 = __shfl(myoff, j + 2);
    int o3 = __shfl(myoff, j + 3);
    unsigned int u0 = *(const unsigned int*)(fb + o0 + lb);
    unsigned int u1 = *(const unsigned int*)(fb + o1 + lb);
    unsigned int u2 = *(const unsigned int*)(fb + o2 + lb);
    unsigned int u3 = *(const unsigned int*)(fb + o3 + lb);
    float w0 = ee[wid][(j + 0) * 4 + hl];
    float w1 = ee[wid][(j + 1) * 4 + hl];
    float w2 = ee[wid][(j + 2) * 4 + hl];
    float w3 = ee[wid][(j + 3) * 4 + hl];
    acc0 += __uint_as_float(u0 << 16) * w0; acc1 += __uint_as_float(u0 & 0xFFFF0000u) * w0;
    acc0 += __uint_as_float(u1 << 16) * w1; acc1 += __uint_as_float(u1 & 0xFFFF0000u) * w1;
    acc0 += __uint_as_float(u2 << 16) * w2; acc1 += __uint_as_float(u2 & 0xFFFF0000u) * w2;
    acc0 += __uint_as_float(u3 << 16) * w3; acc1 += __uint_as_float(u3 & 0xFFFF0000u) * w3;
  }
  for (; j < m64; ++j) {
    int o = __shfl(myoff, j);
    unsigned int u = *(const unsigned int*)(fb + o + lb);
    float w = ee[wid][j * 4 + hl];
    acc0 += __uint_as_float(u << 16) * w; acc1 += __uint_as_float(u & 0xFFFF0000u) * w;
  }
  for (; j < deg; ++j) {
    int o = bk[j];
    unsigned int u = *(const unsigned int*)(fb + o + lb);
    float w = ee[wid][j * 4 + hl];
    acc0 += __uint_as_float(u << 16) * w; acc1 += __uint_as_float(u & 0xFFFF0000u) * w;
  }
  float2 bb = *(const float2*)&b1[lane * 2];
  float o0 = fmaxf(acc0 + bb.x, 0.f);
  float o1 = fmaxf(acc1 + bb.y, 0.f);
  unsigned int p = (unsigned int)f2bf(o0) | ((unsigned int)f2bf(o1) << 16);
  *(unsigned int*)&houtb[n * HID + lane * 2] = p;
}

// ---------------- GEMM2 (MFMA bf16): feat2 = h @ W2, fp32 out ----------------
__global__ __launch_bounds__(256) void gemm2_mfma(const unsigned short* __restrict__ hb,
                                                  const unsigned short* __restrict__ W2T,
                                                  float* __restrict__ feat2) {
  __shared__ unsigned short As[64 * 128];
  __shared__ unsigned short Bs[64 * 128];
  int t = threadIdx.x, lane = t & 63, wid = t >> 6;
  int n0 = blockIdx.x * 64;
  f32x4 acc[4];
#pragma unroll
  for (int n = 0; n < 4; ++n) acc[n] = (f32x4){0.f, 0.f, 0.f, 0.f};

#pragma unroll
  for (int it = 0; it < 4; ++it) {
    int id = it * 256 + t;
    int row = id >> 4, c8 = id & 15;
    int grow = n0 + row;
    uint4 v = make_uint4(0, 0, 0, 0);
    if (grow < NN) v = *(const uint4*)&hb[grow * HID + c8 * 8];
    int byte = row * 256 + c8 * 16;
    byte ^= (row & 15) << 4;
    *(uint4*)((char*)As + byte) = v;
  }
#pragma unroll
  for (int it = 0; it < 4; ++it) {
    int id = it * 256 + t;
    int row = id >> 4, c8 = id & 15;
    uint4 v = *(const uint4*)&W2T[row * 128 + c8 * 8];
    int byte = row * 256 + c8 * 16;
    byte ^= (row & 15) << 4;
    *(uint4*)((char*)Bs + byte) = v;
  }
  __syncthreads();
  int wr = wid * 16;
#pragma unroll
  for (int ks = 0; ks < 4; ++ks) {
    int kb = ks * 64 + (lane >> 4) * 16;
    int arow = wr + (lane & 15);
    int abyte = (arow * 256 + kb) ^ ((arow & 15) << 4);
    short8v a = *(const short8v*)((const char*)As + abyte);
#pragma unroll
    for (int n = 0; n < 4; ++n) {
      int c = n * 16 + (lane & 15);
      int bbyte = (c * 256 + kb) ^ ((c & 15) << 4);
      short8v b = *(const short8v*)((const char*)Bs + bbyte);
      acc[n] = __builtin_amdgcn_mfma_f32_16x16x32_bf16(a, b, acc[n], 0, 0, 0);
    }
  }
  int rbase = n0 + wr + (lane >> 4) * 4;
#pragma unroll
  for (int r = 0; r < 4; ++r) {
    int grow = rbase + r;
    if (grow >= NN) continue;
#pragma unroll
    for (int n = 0; n < 4; ++n)
      feat2[grow * OUTF + n * 16 + (lane & 15)] = acc[n][r];
  }
}

// ---------------- attention scores layer 2: el2/er2 [N] ----------------
__global__ __launch_bounds__(256) void scores2_k(const float* __restrict__ feat2,
                                                 const float* __restrict__ al2,
                                                 const float* __restrict__ ar2,
                                                 float* __restrict__ el2,
                                                 float* __restrict__ er2) {
  int wid = threadIdx.x >> 6, lane = threadIdx.x & 63;
  int n = blockIdx.x * 4 + wid;
  float f = feat2[n * OUTF + lane];
  float pe = f * al2[lane];
  float pr = f * ar2[lane];
#pragma unroll
  for (int off = 1; off < 64; off <<= 1) {
    pe += __shfl_xor(pe, off);
    pr += __shfl_xor(pr, off);
  }
  if (lane == 0) { el2[n] = pe; er2[n] = pr; }
}

// ---------------- layer-2 softmax + aggregation ----------------
__global__ __launch_bounds__(256) void agg2_k(const float* __restrict__ feat2,
                                              const float* __restrict__ el2,
                                              const float* __restrict__ er2,
                                              const float* __restrict__ b2,
                                              const int* __restrict__ counts,
                                              const int* __restrict__ bucket,
                                              float* __restrict__ out) {
  __shared__ float ee[4][CAP];
  int wid = threadIdx.x >> 6, lane = threadIdx.x & 63;
  int n = blockIdx.x * 4 + wid;
  int deg = counts[n]; if (deg > CAP) deg = CAP;
  const int* bk = bucket + n * CAP;
  float er = er2[n];
  int m64 = deg < 64 ? deg : 64;
  int myoff = (lane < m64) ? bk[lane] : -1;

  if (deg <= 64) {
    float sc = -INFINITY;
    if (myoff >= 0)
      sc = lrelu(*(const float*)((const char*)el2 + (myoff >> 6)) + er);
    float mx = sc;
#pragma unroll
    for (int off = 1; off < 64; off <<= 1) mx = fmaxf(mx, __shfl_xor(mx, off));
    float ex = (myoff >= 0) ? __expf(sc - mx) : 0.f;
    float zs = ex;
#pragma unroll
    for (int off = 1; off < 64; off <<= 1) zs += __shfl_xor(zs, off);
    if (myoff >= 0) ee[wid][lane] = ex / zs;
  } else {
    float mx = -INFINITY;
    for (int j = lane; j < deg; j += 64) {
      int o = bk[j];
      mx = fmaxf(mx, lrelu(*(const float*)((const char*)el2 + (o >> 6)) + er));
    }
#pragma unroll
    for (int off = 1; off < 64; off <<= 1) mx = fmaxf(mx, __shfl_xor(mx, off));
    float zs = 0.f;
    for (int j = lane; j < deg; j += 64) {
      int o = bk[j];
      float ex = __expf(lrelu(*(const float*)((const char*)el2 + (o >> 6)) + er) - mx);
      ee[wid][j] = ex;
      zs += ex;
    }
#pragma unroll
    for (int off = 1; off < 64; off <<= 1) zs += __shfl_xor(zs, off);
    float iz = 1.f / zs;
    for (int j = lane; j < deg; j += 64) ee[wid][j] *= iz;
  }

  float acc = 0.f;
  const char* fb = (const char*)feat2;
  int lb = lane * 4;
  int j = 0;
  for (; j + 4 <= m64; j += 4) {
    int o0 = __shfl(myoff, j);
    int o1 = __shfl(myoff, j + 1);
    int o2 = __shfl(myoff, j + 2);
    int o3 = __shfl(myoff, j + 3);
    float f0 = *(const float*)(fb + o0 + lb);
    float f1 = *(const float*)(fb + o1 + lb);
    float f2 = *(const float*)(fb + o2 + lb);
    float f3 = *(const float*)(fb + o3 + lb);
    acc += f0 * ee[wid][j + 0];
    acc += f1 * ee[wid][j + 1];
    acc += f2 * ee[wid][j + 2];
    acc += f3 * ee[wid][j + 3];
  }
  for (; j < m64; ++j) {
    int o = __shfl(myoff, j);
    acc += *(const float*)(fb + o + lb) * ee[wid][j];
  }
  for (; j < deg; ++j) {
    int o = bk[j];
    acc += *(const float*)(fb + o + lb) * ee[wid][j];
  }
  out[n * OUTF + lane] = acc + b2[lane];
}

extern "C" void kernel_launch(void* const* d_in, const int* in_sizes, int n_in,
                              void* d_out, int out_size, void* d_ws, size_t ws_size,
                              hipStream_t stream) {
  const float* x   = (const float*)d_in[0];
  const float* W1  = (const float*)d_in[1];
  const float* al1 = (const float*)d_in[2];
  const float* ar1 = (const float*)d_in[3];
  const float* b1  = (const float*)d_in[4];
  const float* W2  = (const float*)d_in[5];
  const float* al2 = (const float*)d_in[6];
  const float* ar2 = (const float*)d_in[7];
  const float* b2  = (const float*)d_in[8];
  const int*   src = (const int*)d_in[9];
  const int*   dst = (const int*)d_in[10];
  float* out = (float*)d_out;

  char* base = (char*)d_ws;
  unsigned short* feat1b = (unsigned short*)base;                 // N*128 bf16 (12.8 MB)
  float*          feat2  = (float*)base;                          // overlay: N*64 fp32 (12.8 MB)
  unsigned short* hb     = (unsigned short*)(base + 12800000);    // N*128 bf16
  float* el1 = (float*)(base + 25600000);                         // N*4
  float* er1 = el1 + NN * 4;                                      // N*4
  float* el2 = er1 + NN * 4;                                      // N
  float* er2 = el2 + NN;                                          // N
  int* counts = (int*)(er2 + NN);                                 // N
  int* bucket = counts + NN;                                      // N*CAP
  unsigned short* W1T = (unsigned short*)(bucket + NN * CAP);     // 256*128
  unsigned short* W2T = W1T + 256 * 128;                          // 64*128

  hipMemsetAsync(counts, 0, NN * sizeof(int), stream);
  convW1_k  <<<128, 256, 0, stream>>>(W1, W1T);
  convW2_k  <<<32, 256, 0, stream>>>(W2, W2T);
  gemm1_mfma<<<(NN + 63) / 64, 256, 0, stream>>>(x, W1T, feat1b);
  scores1_k <<<NN / 4, 256, 0, stream>>>(feat1b, al1, ar1, el1, er1);
  scatter_k <<<EE / 256, 256, 0, stream>>>(src, dst, counts, bucket);
  agg1_k    <<<NN / 4, 256, 0, stream>>>(feat1b, el1, er1, b1, counts, bucket, hb);
  gemm2_mfma<<<(NN + 63) / 64, 256, 0, stream>>>(hb, W2T, feat2);
  scores2_k <<<NN / 4, 256, 0, stream>>>(feat2, al2, ar2, el2, er2);
  agg2_k    <<<NN / 4, 256, 0, stream>>>(feat2, el2, er2, b2, counts, bucket, out);
}